// Round 16
// baseline (969.405 us; speedup 1.0000x reference)
//
#include <hip/hip_runtime.h>
#include <hip/hip_bf16.h>

typedef __attribute__((ext_vector_type(8))) short s16x8;
typedef __attribute__((ext_vector_type(4))) float f32x4;
typedef __attribute__((ext_vector_type(16))) float f32x16;

#define DEV __device__ __forceinline__

DEV short f2b(float f) {
  __hip_bfloat16 h = __float2bfloat16(f);
  short s; __builtin_memcpy(&s, &h, 2); return s;
}
DEV float b2f(short s) {
  __hip_bfloat16 h; __builtin_memcpy(&h, &s, 2); return __bfloat162float(h);
}

typedef __attribute__((address_space(1))) const void gvoid;
typedef __attribute__((address_space(3))) void lvoid;
DEV void gload_lds16(const void* g, void* l) {
  __builtin_amdgcn_global_load_lds((gvoid*)g, (lvoid*)l, 16, 0, 0);
}

// ---------------- problem dims ----------------
static constexpr int kB = 8192, kP = 9, kDIN = 768, kENCH = 512, kD = 1024;
static constexpr int kE = 8, kH = 2048, kC = 1000;
static constexpr size_t OUT_GATE   = (size_t)kB * kC;            // 8192000
static constexpr size_t OUT_EL     = OUT_GATE + (size_t)kB * kE; // 8257536

// ---------------- ws layout (bytes) ----------------
static constexpr size_t W1T  = 0;                       // 512x768 bf16
static constexpr size_t W2T  = W1T  + 786432;           // 1024x512 bf16
static constexpr size_t GW1T = W2T  + 1048576;          // 1024x1024 bf16
static constexpr size_t EW1T = GW1T + 2097152;          // 8 x 2048x1024 bf16
static constexpr size_t EW2T = EW1T + 33554432;         // 8 x 1000x2048 bf16
static constexpr size_t PBF  = EW2T + 32768000;         // 73728x768 bf16 (dead after enc L1)
static constexpr size_t HBUF = PBF  + 113246208;        // 73728x512 bf16
static constexpr size_t EH4  = HBUF + 75497472;         // up to 8 x 8192x2048 bf16
static constexpr size_t WS_Z8 = EH4 + (size_t)8 * kB * kH * 2;
// region reuse inside PBF after enc L1 / mean:
static constexpr size_t HMEAN = PBF;                    // 8192x512 bf16
static constexpr size_t AGG   = HMEAN + 8388608;        // 8192x1024 bf16
static constexpr size_t GH    = AGG   + 16777216;       // 8192x1024 bf16

// ---------------- cast f32 -> bf16 (8/thread) ----------------
__global__ void cast_bf16_kernel(const float* __restrict__ in, short* __restrict__ out, size_t n8) {
  size_t i = (size_t)blockIdx.x * blockDim.x + threadIdx.x;
  if (i >= n8) return;
  float4 a = ((const float4*)in)[i * 2];
  float4 b = ((const float4*)in)[i * 2 + 1];
  s16x8 v;
  v[0] = f2b(a.x); v[1] = f2b(a.y); v[2] = f2b(a.z); v[3] = f2b(a.w);
  v[4] = f2b(b.x); v[5] = f2b(b.y); v[6] = f2b(b.z); v[7] = f2b(b.w);
  *(s16x8*)(out + i * 8) = v;
}

// ---------------- transpose + cast: W (R x C) f32 -> Wt (C x R) bf16 ----------------
__global__ void transpose_cast_kernel(const float* __restrict__ in, short* __restrict__ out,
                                      int R, int C, size_t istride, size_t ostride) {
  __shared__ float tile[32][33];
  const float* W = in + istride * blockIdx.z;
  short* T = out + ostride * blockIdx.z;
  int tx = threadIdx.x, ty = threadIdx.y;
  int c0 = blockIdx.x * 32, r0 = blockIdx.y * 32;
  #pragma unroll
  for (int i = 0; i < 32; i += 8) {
    int r = r0 + ty + i, c = c0 + tx;
    if (r < R && c < C) tile[ty + i][tx] = W[(size_t)r * C + c];
  }
  __syncthreads();
  #pragma unroll
  for (int i = 0; i < 32; i += 8) {
    int rr = c0 + ty + i, cc = r0 + tx;
    if (rr < C && cc < R) T[(size_t)rr * R + cc] = f2b(tile[tx][ty + i]);
  }
}

// =======================================================================
// 256x256 GEMM — R11/R14 structure (BK=64, 128 KiB LDS, m201-depth
// prefetch, 2 phases/K-tile, 1 barrier/phase, counted vmcnt(6)) with the
// MFMA shape switched 16x16x32 -> 32x32x16 (halves instruction count,
// 15% higher measured pipe ceiling; staging/swizzle bytes unchanged).
// Wave owns 128x64 as 4x2 tiles of 32x32. A/B frag: row(col)=lane&31,
// k8=(lane>>5)*8 [analog of validated 16x16 mapping]. C/D (HW-verified
// m74/m101): col=lane&31, row=(reg&3)+8*(reg>>2)+4*(lane>>5).
// =======================================================================
#define BARR() __builtin_amdgcn_s_barrier()
#define VMW6() asm volatile("s_waitcnt vmcnt(6)" ::: "memory")
#define VMW4() asm volatile("s_waitcnt vmcnt(4)" ::: "memory")
#define VMW0() asm volatile("s_waitcnt vmcnt(0)" ::: "memory")

template<bool RELU, bool F32OUT, bool NTAIL>
__global__ __launch_bounds__(512, 2)
void gemm256_kernel(const short* __restrict__ A, const short* __restrict__ Bt,
                    const float* __restrict__ bias, void* __restrict__ Cout,
                    int M, int N, int K, int ldc,
                    long aZ, long bZ, long biasZ, long cZ) {
  __shared__ short Abuf[2][2][8192];   // [parity][half][128 rows x 64 k]
  __shared__ short Bbuf[2][2][8192];
  const int z = blockIdx.z;
  A += (size_t)z * aZ; Bt += (size_t)z * bZ; bias += (size_t)z * biasZ;

  const int XT = gridDim.x;
  int lid = blockIdx.y * XT + blockIdx.x;
  const int cpx = (XT * gridDim.y) >> 3;
  lid = (lid & 7) * cpx + (lid >> 3);
  const int bx = lid % XT, by = lid / XT;
  const int bM = by * 256, bN = bx * 256;

  const int t = threadIdx.x, lane = t & 63, wid = t >> 6;
  const int wm = wid & 1, wn = wid >> 1;       // wave rows: wm-interleaved halves; cols wn*32
  const int l31 = lane & 31, lg = lane >> 5;   // 32-lane row/col group, k-group
  const int nkt = K >> 6;                      // K-tiles of 64

  // staging geometry (identical to R11/R14): thread t covers LDS row t>>3,
  // slot t&7 (16B); source slot pre-swizzled sx = (t&7) ^ (row&7)
  const int srB = t >> 3;
  const int sx = (t & 7) ^ (srB & 7);
  const int ldsoff = wid * 512;

  int br0 = bN + srB, br1 = bN + 64 + srB, br2 = bN + 128 + srB, br3 = bN + 192 + srB;
  if (NTAIL) {
    if (br0 >= N) br0 = N - 1;
    if (br1 >= N) br1 = N - 1;
    if (br2 >= N) br2 = N - 1;
    if (br3 >= N) br3 = N - 1;
  }
  const short* pA00 = A + (size_t)(bM + srB) * K + sx * 8;
  const short* pA01 = A + (size_t)(bM + 64 + srB) * K + sx * 8;
  const short* pA10 = A + (size_t)(bM + 128 + srB) * K + sx * 8;
  const short* pA11 = A + (size_t)(bM + 192 + srB) * K + sx * 8;
  const short* pB00 = Bt + (size_t)br0 * K + sx * 8;
  const short* pB01 = Bt + (size_t)br1 * K + sx * 8;
  const short* pB10 = Bt + (size_t)br2 * K + sx * 8;
  const short* pB11 = Bt + (size_t)br3 * K + sx * 8;

#define STAGE_A0(tile_) do { if ((tile_) < nkt) { int par_ = (tile_) & 1; \
    gload_lds16(pA00, &Abuf[par_][0][ldsoff]); \
    gload_lds16(pA01, &Abuf[par_][0][4096 + ldsoff]); \
    pA00 += 64; pA01 += 64; } } while (0)
#define STAGE_A1(tile_) do { if ((tile_) < nkt) { int par_ = (tile_) & 1; \
    gload_lds16(pA10, &Abuf[par_][1][ldsoff]); \
    gload_lds16(pA11, &Abuf[par_][1][4096 + ldsoff]); \
    pA10 += 64; pA11 += 64; } } while (0)
#define STAGE_B0(tile_) do { if ((tile_) < nkt) { int par_ = (tile_) & 1; \
    gload_lds16(pB00, &Bbuf[par_][0][ldsoff]); \
    gload_lds16(pB01, &Bbuf[par_][0][4096 + ldsoff]); \
    pB00 += 64; pB01 += 64; } } while (0)
#define STAGE_B1(tile_) do { if ((tile_) < nkt) { int par_ = (tile_) & 1; \
    gload_lds16(pB10, &Bbuf[par_][1][ldsoff]); \
    gload_lds16(pB11, &Bbuf[par_][1][4096 + ldsoff]); \
    pB10 += 64; pB11 += 64; } } while (0)

  // fragment-read bases (shorts): row*64; slot for k-slice s: ((2s+lg)^(lane&7))*8
  const int arb0 = (wm * 64 + l31) * 64;        // A sub-tile 0 (rows +0..31)
  const int arb1 = (wm * 64 + 32 + l31) * 64;   // A sub-tile 1 (rows +32..63)
  const int brb  = (wn * 32 + l31) * 64;
  const int l7 = lane & 7;

  s16x8 a[2][4], b0[4], b1[4];
#define LDA(mh_, par_) do { _Pragma("unroll") \
    for (int s_ = 0; s_ < 4; ++s_) { \
      int so_ = ((2 * s_ + lg) ^ l7) * 8; \
      a[0][s_] = *(const s16x8*)&Abuf[par_][mh_][arb0 + so_]; \
      a[1][s_] = *(const s16x8*)&Abuf[par_][mh_][arb1 + so_]; \
    } } while (0)
#define LDB(nh_, BF, par_) do { _Pragma("unroll") \
    for (int s_ = 0; s_ < 4; ++s_) { \
      int so_ = ((2 * s_ + lg) ^ l7) * 8; \
      BF[s_] = *(const s16x8*)&Bbuf[par_][nh_][brb + so_]; \
    } } while (0)

  f32x16 acc[4][2];   // [tr = mh*2 + sub][tc = nh]
  #pragma unroll
  for (int i_ = 0; i_ < 4; ++i_)
    #pragma unroll
    for (int j_ = 0; j_ < 2; ++j_)
      #pragma unroll
      for (int r_ = 0; r_ < 16; ++r_) acc[i_][j_][r_] = 0.f;

#define MMAQ(mh_, nh_, BF) do { \
    __builtin_amdgcn_s_setprio(1); \
    _Pragma("unroll") \
    for (int s_ = 0; s_ < 4; ++s_) { \
      acc[(mh_) * 2 + 0][nh_] = __builtin_amdgcn_mfma_f32_32x32x16_bf16(a[0][s_], BF[s_], acc[(mh_) * 2 + 0][nh_], 0, 0, 0); \
      acc[(mh_) * 2 + 1][nh_] = __builtin_amdgcn_mfma_f32_32x32x16_bf16(a[1][s_], BF[s_], acc[(mh_) * 2 + 1][nh_], 0, 0, 0); \
    } \
    __builtin_amdgcn_s_setprio(0); } while (0)

  // ---- prologue: tile0{A0,B0,B1,A1} + tile1{A0,B0,B1} ----
  STAGE_A0(0); STAGE_B0(0); STAGE_B1(0); STAGE_A1(0);
  VMW4();
  STAGE_A0(1); STAGE_B0(1); STAGE_B1(1);
  VMW6();
  BARR();

  // ---- main loop: 2 phases per K-tile (R11-validated sync) ----
  for (int g = 0; g < nkt; ++g) {
    const int par = g & 1;
    // Ph1: quadrants (0,0),(0,1)
    LDA(0, par); LDB(0, b0, par); LDB(1, b1, par);
    STAGE_A1(g + 1);
    MMAQ(0, 0, b0);
    MMAQ(0, 1, b1);
    BARR();
    // Ph2: quadrants (1,1),(1,0) — b0/b1 held in regs
    LDA(1, par);
    STAGE_A0(g + 2); STAGE_B0(g + 2); STAGE_B1(g + 2);
    MMAQ(1, 1, b1);
    MMAQ(1, 0, b0);
    if (g == nkt - 2) { VMW0(); } else if (g < nkt - 2) { VMW6(); }
    BARR();
  }

  // ---- epilogue: C/D map col=lane&31, row=(r&3)+8*(r>>2)+4*lg ----
  #pragma unroll
  for (int tc = 0; tc < 2; ++tc) {
    int col = bN + tc * 128 + wn * 32 + l31;
    if (NTAIL && col >= N) continue;
    float bv = bias[col];
    #pragma unroll
    for (int tr = 0; tr < 4; ++tr) {
      int rbase = bM + (tr >> 1) * 128 + wm * 64 + (tr & 1) * 32 + 4 * lg;
      #pragma unroll
      for (int r_ = 0; r_ < 16; ++r_) {
        int row = rbase + (r_ & 3) + 8 * (r_ >> 2);
        float v = acc[tr][tc][r_] + bv;
        if (RELU) v = fmaxf(v, 0.f);
        size_t off = (size_t)row * ldc + col;
        if (F32OUT) ((float*)Cout + (size_t)z * cZ)[off] = v;
        else        ((short*)Cout + (size_t)z * cZ)[off] = f2b(v);
      }
    }
  }
#undef STAGE_A0
#undef STAGE_A1
#undef STAGE_B0
#undef STAGE_B1
#undef LDA
#undef LDB
#undef MMAQ
}

// =======================================================================
// 128x256 GEMM (R13, 16x16x32 — verified): BK=32, 48 KiB LDS, 2 blocks/CU.
// For the small GEMMs (enc-L2, gating-L1).
// =======================================================================
template<bool RELU, bool F32OUT, bool NTAIL>
__global__ __launch_bounds__(512, 4)
void gemm128_kernel(const short* __restrict__ A, const short* __restrict__ Bt,
                    const float* __restrict__ bias, void* __restrict__ Cout,
                    int M, int N, int K, int ldc,
                    long aZ, long bZ, long biasZ, long cZ) {
  __shared__ short Abuf[2][4096];
  __shared__ short Bbuf[2][2][4096];
  const int z = blockIdx.z;
  A += (size_t)z * aZ; Bt += (size_t)z * bZ; bias += (size_t)z * biasZ;

  const int XT = gridDim.x;
  int lid = blockIdx.y * XT + blockIdx.x;
  const int cpx = (XT * gridDim.y) >> 3;
  lid = (lid & 7) * cpx + (lid >> 3);
  const int bx = lid % XT, by = lid / XT;
  const int bM = by * 128, bN = bx * 256;

  const int t = threadIdx.x, lane = t & 63, wid = t >> 6;
  const int wm = wid & 1, wn = wid >> 1;
  const int lr = lane & 15, kg = lane >> 4;
  const int nkt = K >> 5;

  const int srB = t >> 2;
  const int sx = (t & 3) ^ ((srB >> 1) & 3);
  const int ldsoff = wid * 512;

  int br0 = bN + srB, br1 = bN + 128 + srB;
  if (NTAIL) {
    if (br0 >= N) br0 = N - 1;
    if (br1 >= N) br1 = N - 1;
  }
  const short* pA  = A + (size_t)(bM + srB) * K + sx * 8;
  const short* pB0 = Bt + (size_t)br0 * K + sx * 8;
  const short* pB1 = Bt + (size_t)br1 * K + sx * 8;

#define STAGE(tile_) do { if ((tile_) < nkt) { int par_ = (tile_) & 1; \
    gload_lds16(pA,  &Abuf[par_][ldsoff]); \
    gload_lds16(pB0, &Bbuf[par_][0][ldsoff]); \
    gload_lds16(pB1, &Bbuf[par_][1][ldsoff]); \
    pA += 32; pB0 += 32; pB1 += 32; } } while (0)

  const int aro = (wm * 64 + lr) * 32;
  const int bro = (wn * 32 + lr) * 32;
  const int so = (kg ^ ((lr >> 1) & 3)) * 8;

  s16x8 a[4], b0[2], b1[2];
#define LDFRAGS(par_) do { \
    _Pragma("unroll") \
    for (int m_ = 0; m_ < 4; ++m_) a[m_] = *(const s16x8*)&Abuf[par_][aro + m_ * 512 + so]; \
    _Pragma("unroll") \
    for (int n_ = 0; n_ < 2; ++n_) { \
      b0[n_] = *(const s16x8*)&Bbuf[par_][0][bro + n_ * 512 + so]; \
      b1[n_] = *(const s16x8*)&Bbuf[par_][1][bro + n_ * 512 + so]; \
    } } while (0)

  f32x4 acc[2][4][2];
  #pragma unroll
  for (int h_ = 0; h_ < 2; ++h_)
    #pragma unroll
    for (int m_ = 0; m_ < 4; ++m_)
      #pragma unroll
      for (int n_ = 0; n_ < 2; ++n_) acc[h_][m_][n_] = (f32x4){0.f, 0.f, 0.f, 0.f};

  STAGE(0);
  VMW0();
  BARR();

  for (int g = 0; g < nkt; ++g) {
    const int par = g & 1;
    LDFRAGS(par);
    STAGE(g + 1);
    __builtin_amdgcn_s_setprio(1);
    #pragma unroll
    for (int m_ = 0; m_ < 4; ++m_)
      #pragma unroll
      for (int n_ = 0; n_ < 2; ++n_) {
        acc[0][m_][n_] = __builtin_amdgcn_mfma_f32_16x16x32_bf16(a[m_], b0[n_], acc[0][m_][n_], 0, 0, 0);
        acc[1][m_][n_] = __builtin_amdgcn_mfma_f32_16x16x32_bf16(a[m_], b1[n_], acc[1][m_][n_], 0, 0, 0);
      }
    __builtin_amdgcn_s_setprio(0);
    VMW0();
    BARR();
  }

  #pragma unroll
  for (int nh = 0; nh < 2; ++nh)
    #pragma unroll
    for (int n_ = 0; n_ < 2; ++n_) {
      int col = bN + nh * 128 + wn * 32 + n_ * 16 + lr;
      if (NTAIL && col >= N) continue;
      float bv = bias[col];
      #pragma unroll
      for (int m_ = 0; m_ < 4; ++m_) {
        int row0 = bM + wm * 64 + m_ * 16 + kg * 4;
        #pragma unroll
        for (int r_ = 0; r_ < 4; ++r_) {
          float v = acc[nh][m_][n_][r_] + bv;
          if (RELU) v = fmaxf(v, 0.f);
          size_t off = (size_t)(row0 + r_) * ldc + col;
          if (F32OUT) ((float*)Cout + (size_t)z * cZ)[off] = v;
          else        ((short*)Cout + (size_t)z * cZ)[off] = f2b(v);
        }
      }
    }
#undef STAGE
#undef LDFRAGS
}

// ---------------- mean over 9 patch rows (vectorized s16x8) ----------------
__global__ void mean9_kernel(const short* __restrict__ h, short* __restrict__ hm) {
  size_t i = (size_t)blockIdx.x * blockDim.x + threadIdx.x;
  if (i >= (size_t)kB * kENCH / 8) return;
  size_t b = i >> 6; int d8 = (int)(i & 63);
  const short* base = h + b * kP * kENCH + d8 * 8;
  float s[8] = {0, 0, 0, 0, 0, 0, 0, 0};
  #pragma unroll
  for (int p = 0; p < kP; ++p) {
    s16x8 v = *(const s16x8*)(base + p * kENCH);
    #pragma unroll
    for (int j = 0; j < 8; ++j) s[j] += b2f(v[j]);
  }
  s16x8 o;
  #pragma unroll
  for (int j = 0; j < 8; ++j) o[j] = f2b(s[j] * (1.f / 9.f));
  *(s16x8*)(hm + i * 8) = o;
}

// ---------------- fused gating: neural L2 + symbolic MLP + softmax --------
__global__ __launch_bounds__(256)
void gating_fused_kernel(const short* __restrict__ gh,
                         const float* __restrict__ gn_w2, const float* __restrict__ gn_b2,
                         const float* __restrict__ sym,
                         const float* __restrict__ gs_w1, const float* __restrict__ gs_b1,
                         const float* __restrict__ gs_w2, const float* __restrict__ gs_b2,
                         float* __restrict__ gate_out) {
  int wid = threadIdx.x >> 6, lane = threadIdx.x & 63;
  int row = blockIdx.x * 4 + wid;
  float acc[8] = {0,0,0,0,0,0,0,0};
  const short* grow = gh + (size_t)row * kD;
  for (int k = lane; k < kD; k += 64) {
    float x = b2f(grow[k]);
    const float* w = gn_w2 + (size_t)k * 8;
    #pragma unroll
    for (int c = 0; c < 8; ++c) acc[c] += x * w[c];
  }
  float s0 = sym[(size_t)row * 6 + 0], s1 = sym[(size_t)row * 6 + 1], s2 = sym[(size_t)row * 6 + 2];
  float s3 = sym[(size_t)row * 6 + 3], s4 = sym[(size_t)row * 6 + 4], s5 = sym[(size_t)row * 6 + 5];
  float hh = gs_b1[lane];
  hh += s0 * gs_w1[0 * 64 + lane] + s1 * gs_w1[1 * 64 + lane] + s2 * gs_w1[2 * 64 + lane];
  hh += s3 * gs_w1[3 * 64 + lane] + s4 * gs_w1[4 * 64 + lane] + s5 * gs_w1[5 * 64 + lane];
  hh = fmaxf(hh, 0.f);
  float acc2[8];
  #pragma unroll
  for (int c = 0; c < 8; ++c) acc2[c] = hh * gs_w2[lane * 8 + c];
  #pragma unroll
  for (int c = 0; c < 8; ++c)
    #pragma unroll
    for (int off = 32; off >= 1; off >>= 1) {
      acc[c]  += __shfl_xor(acc[c], off);
      acc2[c] += __shfl_xor(acc2[c], off);
    }
  if (lane == 0) {
    float g[8], m = -1e30f;
    #pragma unroll
    for (int c = 0; c < 8; ++c) {
      g[c] = 0.5f * ((acc[c] + gn_b2[c]) + (acc2[c] + gs_b2[c]));
      m = fmaxf(m, g[c]);
    }
    float sum = 0.f;
    #pragma unroll
    for (int c = 0; c < 8; ++c) { g[c] = expf(g[c] - m); sum += g[c]; }
    float inv = 1.f / sum;
    #pragma unroll
    for (int c = 0; c < 8; ++c) gate_out[(size_t)row * 8 + c] = g[c] * inv;
  }
}

// ---------------- logits[b,c] = sum_e gate[b,e] * EL[b,e,c] ----------------
__global__ __launch_bounds__(256)
void combine_kernel(float* __restrict__ out) {
  int b = blockIdx.y;
  int c = blockIdx.x * 256 + threadIdx.x;
  __shared__ float g[8];
  if (threadIdx.x < 8) g[threadIdx.x] = out[OUT_GATE + (size_t)b * 8 + threadIdx.x];
  __syncthreads();
  if (c < kC) {
    const float* el = out + OUT_EL + (size_t)b * (kE * kC) + c;
    float a = 0.f;
    #pragma unroll
    for (int e = 0; e < 8; ++e) a += g[e] * el[e * kC];
    out[(size_t)b * kC + c] = a;
  }
}

extern "C" void kernel_launch(void* const* d_in, const int* in_sizes, int n_in,
                              void* d_out, int out_size, void* d_ws, size_t ws_size,
                              hipStream_t stream) {
  const float* patches = (const float*)d_in[0];
  const float* symf    = (const float*)d_in[1];
  const float* enc_w1  = (const float*)d_in[2];
  const float* enc_b1  = (const float*)d_in[3];
  const float* enc_w2  = (const float*)d_in[4];
  const float* enc_b2  = (const float*)d_in[5];
  const float* gn_w1   = (const float*)d_in[6];
  const float* gn_b1   = (const float*)d_in[7];
  const float* gn_w2   = (const float*)d_in[8];
  const float* gn_b2   = (const float*)d_in[9];
  const float* gs_w1   = (const float*)d_in[10];
  const float* gs_b1   = (const float*)d_in[11];
  const float* gs_w2   = (const float*)d_in[12];
  const float* gs_b2   = (const float*)d_in[13];
  const float* ew1     = (const float*)d_in[14];
  const float* eb1     = (const float*)d_in[15];
  const float* ew2     = (const float*)d_in[16];
  const float* eb2     = (const float*)d_in[17];
  char* ws = (char*)d_ws;
  float* out = (float*)d_out;
  dim3 tb(32, 8);

  // 1. cast patches to bf16 (viewed as 73728 x 768)
  {
    size_t n8 = (size_t)kB * kP * kDIN / 8;
    cast_bf16_kernel<<<(unsigned)((n8 + 255) / 256), 256, 0, stream>>>(patches, (short*)(ws + PBF), n8);
  }
  // 2. transpose-cast weights to (N x K) bf16
  transpose_cast_kernel<<<dim3(16, 24, 1), tb, 0, stream>>>(enc_w1, (short*)(ws + W1T),  kDIN,  kENCH, 0, 0);
  transpose_cast_kernel<<<dim3(32, 16, 1), tb, 0, stream>>>(enc_w2, (short*)(ws + W2T),  kENCH, kD,    0, 0);
  transpose_cast_kernel<<<dim3(32, 32, 1), tb, 0, stream>>>(gn_w1,  (short*)(ws + GW1T), kD,    kD,    0, 0);
  transpose_cast_kernel<<<dim3(64, 32, 8), tb, 0, stream>>>(ew1,    (short*)(ws + EW1T), kD,    kH,
                                                            (size_t)kD * kH, (size_t)kD * kH);
  transpose_cast_kernel<<<dim3(32, 64, 8), tb, 0, stream>>>(ew2,    (short*)(ws + EW2T), kH,    kC,
                                                            (size_t)kH * kC, (size_t)kH * kC);
  // 3. encoder L1 (256^2, 32x32 MFMA): (73728x768)@(768x512)^T + b, ReLU -> HBUF
  gemm256_kernel<true, false, false><<<dim3(2, 288, 1), 512, 0, stream>>>(
      (short*)(ws + PBF), (short*)(ws + W1T), enc_b1, ws + HBUF,
      kB * kP, kENCH, kDIN, kENCH, 0, 0, 0, 0);
  // 4. mean over 9 patches -> hmean
  mean9_kernel<<<(kB * kENCH / 8) / 256, 256, 0, stream>>>((short*)(ws + HBUF), (short*)(ws + HMEAN));
  // 5. encoder L2 (128-tile): (8192x512)@(512x1024)^T -> agg
  gemm128_kernel<false, false, false><<<dim3(4, 64, 1), 512, 0, stream>>>(
      (short*)(ws + HMEAN), (short*)(ws + W2T), enc_b2, ws + AGG,
      kB, kD, kENCH, kD, 0, 0, 0, 0);
  // 6. neural gating L1 (128-tile): (8192x1024)@(1024x1024)^T, ReLU -> gh
  gemm128_kernel<true, false, false><<<dim3(4, 64, 1), 512, 0, stream>>>(
      (short*)(ws + AGG), (short*)(ws + GW1T), gn_b1, ws + GH,
      kB, kD, kD, kD, 0, 0, 0, 0);
  // 7. fused gating -> d_out gate
  gating_fused_kernel<<<kB / 4, 256, 0, stream>>>(
      (short*)(ws + GH), gn_w2, gn_b2, symf, gs_w1, gs_b1, gs_w2, gs_b2, out + OUT_GATE);
  // 8-9. experts (R14 z=8 config — best measured)
  if (ws_size >= WS_Z8) {
    gemm256_kernel<true, false, false><<<dim3(8, 32, 8), 512, 0, stream>>>(
        (short*)(ws + AGG), (short*)(ws + EW1T), eb1,
        ws + EH4, kB, kH, kD, kH,
        0, (long)kH * kD, kH, (long)kB * kH);
    gemm256_kernel<false, true, true><<<dim3(4, 32, 8), 512, 0, stream>>>(
        (short*)(ws + EH4), (short*)(ws + EW2T), eb2,
        out + OUT_EL, kB, kC, kH, kE * kC,
        (long)kB * kH, (long)kC * kH, kC, kC);
  } else {
    for (int h = 0; h < 2; ++h) {
      int e0 = h * 4;
      gemm256_kernel<true, false, false><<<dim3(8, 32, 4), 512, 0, stream>>>(
          (short*)(ws + AGG), (short*)(ws + EW1T) + (size_t)e0 * kH * kD, eb1 + (size_t)e0 * kH,
          ws + EH4, kB, kH, kD, kH,
          0, (long)kH * kD, kH, (long)kB * kH);
      gemm256_kernel<false, true, true><<<dim3(4, 32, 4), 512, 0, stream>>>(
          (short*)(ws + EH4), (short*)(ws + EW2T) + (size_t)e0 * kC * kH, eb2 + (size_t)e0 * kC,
          out + OUT_EL + (size_t)e0 * kC, kB, kC, kH, kE * kC,
          (long)kB * kH, (long)kC * kH, kC, kC);
    }
  }
  // 10. combine
  combine_kernel<<<dim3(4, kB), 256, 0, stream>>>(out);
}

// Round 17
// 960.434 us; speedup vs baseline: 1.0093x; 1.0093x over previous
//
#include <hip/hip_runtime.h>
#include <hip/hip_bf16.h>

typedef __attribute__((ext_vector_type(8))) short s16x8;
typedef __attribute__((ext_vector_type(4))) float f32x4;

#define DEV __device__ __forceinline__

DEV short f2b(float f) {
  __hip_bfloat16 h = __float2bfloat16(f);
  short s; __builtin_memcpy(&s, &h, 2); return s;
}
DEV float b2f(short s) {
  __hip_bfloat16 h; __builtin_memcpy(&h, &s, 2); return __bfloat162float(h);
}

typedef __attribute__((address_space(1))) const void gvoid;
typedef __attribute__((address_space(3))) void lvoid;
DEV void gload_lds16(const void* g, void* l) {
  __builtin_amdgcn_global_load_lds((gvoid*)g, (lvoid*)l, 16, 0, 0);
}

// ---------------- problem dims ----------------
static constexpr int kB = 8192, kP = 9, kDIN = 768, kENCH = 512, kD = 1024;
static constexpr int kE = 8, kH = 2048, kC = 1000;
static constexpr size_t OUT_GATE   = (size_t)kB * kC;            // 8192000
static constexpr size_t OUT_EL     = OUT_GATE + (size_t)kB * kE; // 8257536

// ---------------- ws layout (bytes) ----------------
static constexpr size_t W1T  = 0;                       // 512x768 bf16
static constexpr size_t W2T  = W1T  + 786432;           // 1024x512 bf16
static constexpr size_t GW1T = W2T  + 1048576;          // 1024x1024 bf16
static constexpr size_t EW1T = GW1T + 2097152;          // 8 x 2048x1024 bf16
static constexpr size_t EW2T = EW1T + 33554432;         // 8 x 1000x2048 bf16
static constexpr size_t PBF  = EW2T + 32768000;         // 73728x768 bf16 (dead after enc L1)
static constexpr size_t HBUF = PBF  + 113246208;        // 73728x512 bf16
static constexpr size_t EH4  = HBUF + 75497472;         // up to 8 x 8192x2048 bf16
static constexpr size_t WS_Z8 = EH4 + (size_t)8 * kB * kH * 2;
// region reuse inside PBF after enc L1 / mean:
static constexpr size_t HMEAN = PBF;                    // 8192x512 bf16
static constexpr size_t AGG   = HMEAN + 8388608;        // 8192x1024 bf16
static constexpr size_t GH    = AGG   + 16777216;       // 8192x1024 bf16

// ---------------- cast f32 -> bf16 (8/thread) ----------------
__global__ void cast_bf16_kernel(const float* __restrict__ in, short* __restrict__ out, size_t n8) {
  size_t i = (size_t)blockIdx.x * blockDim.x + threadIdx.x;
  if (i >= n8) return;
  float4 a = ((const float4*)in)[i * 2];
  float4 b = ((const float4*)in)[i * 2 + 1];
  s16x8 v;
  v[0] = f2b(a.x); v[1] = f2b(a.y); v[2] = f2b(a.z); v[3] = f2b(a.w);
  v[4] = f2b(b.x); v[5] = f2b(b.y); v[6] = f2b(b.z); v[7] = f2b(b.w);
  *(s16x8*)(out + i * 8) = v;
}

// ---------------- transpose + cast: W (R x C) f32 -> Wt (C x R) bf16 ----------------
__global__ void transpose_cast_kernel(const float* __restrict__ in, short* __restrict__ out,
                                      int R, int C, size_t istride, size_t ostride) {
  __shared__ float tile[32][33];
  const float* W = in + istride * blockIdx.z;
  short* T = out + ostride * blockIdx.z;
  int tx = threadIdx.x, ty = threadIdx.y;
  int c0 = blockIdx.x * 32, r0 = blockIdx.y * 32;
  #pragma unroll
  for (int i = 0; i < 32; i += 8) {
    int r = r0 + ty + i, c = c0 + tx;
    if (r < R && c < C) tile[ty + i][tx] = W[(size_t)r * C + c];
  }
  __syncthreads();
  #pragma unroll
  for (int i = 0; i < 32; i += 8) {
    int rr = c0 + ty + i, cc = r0 + tx;
    if (rr < C && cc < R) T[(size_t)rr * R + cc] = f2b(tile[tx][ty + i]);
  }
}

// =======================================================================
// 256x256 GEMM (best measured config, R11/R14): 16x16x32 MFMA, BK=64,
// 128 KiB LDS, m201-depth prefetch, 2 phases/K-tile, 1 barrier/phase,
// counted vmcnt(6). 16-row fragment reads keep the XOR swizzle 2-way
// (free); 32x32 MFMA was tried (R16) and is inherently 4-way conflicted
// at this layout. WAR/RAW derivation in R10/R11 notes.
// =======================================================================
#define BARR() __builtin_amdgcn_s_barrier()
#define VMW6() asm volatile("s_waitcnt vmcnt(6)" ::: "memory")
#define VMW4() asm volatile("s_waitcnt vmcnt(4)" ::: "memory")
#define VMW0() asm volatile("s_waitcnt vmcnt(0)" ::: "memory")

template<bool RELU, bool F32OUT, bool NTAIL>
__global__ __launch_bounds__(512, 2)
void gemm256_kernel(const short* __restrict__ A, const short* __restrict__ Bt,
                    const float* __restrict__ bias, void* __restrict__ Cout,
                    int M, int N, int K, int ldc,
                    long aZ, long bZ, long biasZ, long cZ) {
  __shared__ short Abuf[2][2][8192];
  __shared__ short Bbuf[2][2][8192];
  const int z = blockIdx.z;
  A += (size_t)z * aZ; Bt += (size_t)z * bZ; bias += (size_t)z * biasZ;

  const int XT = gridDim.x;
  int lid = blockIdx.y * XT + blockIdx.x;
  const int cpx = (XT * gridDim.y) >> 3;
  lid = (lid & 7) * cpx + (lid >> 3);
  const int bx = lid % XT, by = lid / XT;
  const int bM = by * 256, bN = bx * 256;

  const int t = threadIdx.x, lane = t & 63, wid = t >> 6;
  const int wm = wid & 1, wn = wid >> 1;
  const int lr = lane & 15, kg = lane >> 4;
  const int nkt = K >> 6;

  const int srB = t >> 3;
  const int sx = (t & 7) ^ (srB & 7);
  const int ldsoff = wid * 512;

  int br0 = bN + srB, br1 = bN + 64 + srB, br2 = bN + 128 + srB, br3 = bN + 192 + srB;
  if (NTAIL) {
    if (br0 >= N) br0 = N - 1;
    if (br1 >= N) br1 = N - 1;
    if (br2 >= N) br2 = N - 1;
    if (br3 >= N) br3 = N - 1;
  }
  const short* pA00 = A + (size_t)(bM + srB) * K + sx * 8;
  const short* pA01 = A + (size_t)(bM + 64 + srB) * K + sx * 8;
  const short* pA10 = A + (size_t)(bM + 128 + srB) * K + sx * 8;
  const short* pA11 = A + (size_t)(bM + 192 + srB) * K + sx * 8;
  const short* pB00 = Bt + (size_t)br0 * K + sx * 8;
  const short* pB01 = Bt + (size_t)br1 * K + sx * 8;
  const short* pB10 = Bt + (size_t)br2 * K + sx * 8;
  const short* pB11 = Bt + (size_t)br3 * K + sx * 8;

#define STAGE_A0(tile_) do { if ((tile_) < nkt) { int par_ = (tile_) & 1; \
    gload_lds16(pA00, &Abuf[par_][0][ldsoff]); \
    gload_lds16(pA01, &Abuf[par_][0][4096 + ldsoff]); \
    pA00 += 64; pA01 += 64; } } while (0)
#define STAGE_A1(tile_) do { if ((tile_) < nkt) { int par_ = (tile_) & 1; \
    gload_lds16(pA10, &Abuf[par_][1][ldsoff]); \
    gload_lds16(pA11, &Abuf[par_][1][4096 + ldsoff]); \
    pA10 += 64; pA11 += 64; } } while (0)
#define STAGE_B0(tile_) do { if ((tile_) < nkt) { int par_ = (tile_) & 1; \
    gload_lds16(pB00, &Bbuf[par_][0][ldsoff]); \
    gload_lds16(pB01, &Bbuf[par_][0][4096 + ldsoff]); \
    pB00 += 64; pB01 += 64; } } while (0)
#define STAGE_B1(tile_) do { if ((tile_) < nkt) { int par_ = (tile_) & 1; \
    gload_lds16(pB10, &Bbuf[par_][1][ldsoff]); \
    gload_lds16(pB11, &Bbuf[par_][1][4096 + ldsoff]); \
    pB10 += 64; pB11 += 64; } } while (0)

  const int aro = (wm * 64 + lr) * 64;
  const int bro = (wn * 32 + lr) * 64;
  const int so0 = (kg ^ (lr & 7)) * 8;
  const int so1 = ((4 + kg) ^ (lr & 7)) * 8;

  s16x8 a0[4][2], a1[4][2], b0[2][2], b1[2][2];
#define LDA0(par_) do { _Pragma("unroll") \
    for (int m_ = 0; m_ < 4; ++m_) { \
      a0[m_][0] = *(const s16x8*)&Abuf[par_][0][aro + m_ * 1024 + so0]; \
      a0[m_][1] = *(const s16x8*)&Abuf[par_][0][aro + m_ * 1024 + so1]; \
    } } while (0)
#define LDA1(par_) do { _Pragma("unroll") \
    for (int m_ = 0; m_ < 4; ++m_) { \
      a1[m_][0] = *(const s16x8*)&Abuf[par_][1][aro + m_ * 1024 + so0]; \
      a1[m_][1] = *(const s16x8*)&Abuf[par_][1][aro + m_ * 1024 + so1]; \
    } } while (0)
#define LDB0(par_) do { _Pragma("unroll") \
    for (int n_ = 0; n_ < 2; ++n_) { \
      b0[n_][0] = *(const s16x8*)&Bbuf[par_][0][bro + n_ * 1024 + so0]; \
      b0[n_][1] = *(const s16x8*)&Bbuf[par_][0][bro + n_ * 1024 + so1]; \
    } } while (0)
#define LDB1(par_) do { _Pragma("unroll") \
    for (int n_ = 0; n_ < 2; ++n_) { \
      b1[n_][0] = *(const s16x8*)&Bbuf[par_][1][bro + n_ * 1024 + so0]; \
      b1[n_][1] = *(const s16x8*)&Bbuf[par_][1][bro + n_ * 1024 + so1]; \
    } } while (0)

  f32x4 acc[2][2][4][2];
  #pragma unroll
  for (int a_ = 0; a_ < 2; ++a_)
    #pragma unroll
    for (int b_ = 0; b_ < 2; ++b_)
      #pragma unroll
      for (int m_ = 0; m_ < 4; ++m_)
        #pragma unroll
        for (int n_ = 0; n_ < 2; ++n_) acc[a_][b_][m_][n_] = (f32x4){0.f, 0.f, 0.f, 0.f};

#define MMAQ(mh, nh, AF, BF) do { \
    __builtin_amdgcn_s_setprio(1); \
    _Pragma("unroll") \
    for (int m_ = 0; m_ < 4; ++m_) \
      _Pragma("unroll") \
      for (int n_ = 0; n_ < 2; ++n_) { \
        acc[mh][nh][m_][n_] = __builtin_amdgcn_mfma_f32_16x16x32_bf16(AF[m_][0], BF[n_][0], acc[mh][nh][m_][n_], 0, 0, 0); \
        acc[mh][nh][m_][n_] = __builtin_amdgcn_mfma_f32_16x16x32_bf16(AF[m_][1], BF[n_][1], acc[mh][nh][m_][n_], 0, 0, 0); \
      } \
    __builtin_amdgcn_s_setprio(0); } while (0)

  STAGE_A0(0); STAGE_B0(0); STAGE_B1(0); STAGE_A1(0);
  VMW4();
  STAGE_A0(1); STAGE_B0(1); STAGE_B1(1);
  VMW6();
  BARR();

  for (int g = 0; g < nkt; ++g) {
    const int par = g & 1;
    LDA0(par); LDB0(par); LDB1(par);
    STAGE_A1(g + 1);
    MMAQ(0, 0, a0, b0);
    MMAQ(0, 1, a0, b1);
    BARR();
    LDA1(par);
    STAGE_A0(g + 2); STAGE_B0(g + 2); STAGE_B1(g + 2);
    MMAQ(1, 1, a1, b1);
    MMAQ(1, 0, a1, b0);
    if (g == nkt - 2) { VMW0(); } else if (g < nkt - 2) { VMW6(); }
    BARR();
  }

  #pragma unroll
  for (int nh = 0; nh < 2; ++nh)
    #pragma unroll
    for (int n_ = 0; n_ < 2; ++n_) {
      int col = bN + nh * 128 + wn * 32 + n_ * 16 + lr;
      if (NTAIL && col >= N) continue;
      float bv = bias[col];
      #pragma unroll
      for (int mh = 0; mh < 2; ++mh)
        #pragma unroll
        for (int m_ = 0; m_ < 4; ++m_) {
          int row0 = bM + mh * 128 + wm * 64 + m_ * 16 + kg * 4;
          #pragma unroll
          for (int r_ = 0; r_ < 4; ++r_) {
            float v = acc[mh][nh][m_][n_][r_] + bv;
            if (RELU) v = fmaxf(v, 0.f);
            size_t off = (size_t)(row0 + r_) * ldc + col;
            if (F32OUT) ((float*)Cout + (size_t)z * cZ)[off] = v;
            else        ((short*)Cout + (size_t)z * cZ)[off] = f2b(v);
          }
        }
    }
#undef STAGE_A0
#undef STAGE_A1
#undef STAGE_B0
#undef STAGE_B1
#undef LDA0
#undef LDA1
#undef LDB0
#undef LDB1
#undef MMAQ
}

// =======================================================================
// 128x256 GEMM (R13): BK=32, 48 KiB LDS, 2 blocks/CU — for the small
// GEMMs (enc-L2, gating-L1) where a 256^2 grid leaves half the CUs idle.
// =======================================================================
template<bool RELU, bool F32OUT, bool NTAIL>
__global__ __launch_bounds__(512, 4)
void gemm128_kernel(const short* __restrict__ A, const short* __restrict__ Bt,
                    const float* __restrict__ bias, void* __restrict__ Cout,
                    int M, int N, int K, int ldc,
                    long aZ, long bZ, long biasZ, long cZ) {
  __shared__ short Abuf[2][4096];
  __shared__ short Bbuf[2][2][4096];
  const int z = blockIdx.z;
  A += (size_t)z * aZ; Bt += (size_t)z * bZ; bias += (size_t)z * biasZ;

  const int XT = gridDim.x;
  int lid = blockIdx.y * XT + blockIdx.x;
  const int cpx = (XT * gridDim.y) >> 3;
  lid = (lid & 7) * cpx + (lid >> 3);
  const int bx = lid % XT, by = lid / XT;
  const int bM = by * 128, bN = bx * 256;

  const int t = threadIdx.x, lane = t & 63, wid = t >> 6;
  const int wm = wid & 1, wn = wid >> 1;
  const int lr = lane & 15, kg = lane >> 4;
  const int nkt = K >> 5;

  const int srB = t >> 2;
  const int sx = (t & 3) ^ ((srB >> 1) & 3);
  const int ldsoff = wid * 512;

  int br0 = bN + srB, br1 = bN + 128 + srB;
  if (NTAIL) {
    if (br0 >= N) br0 = N - 1;
    if (br1 >= N) br1 = N - 1;
  }
  const short* pA  = A + (size_t)(bM + srB) * K + sx * 8;
  const short* pB0 = Bt + (size_t)br0 * K + sx * 8;
  const short* pB1 = Bt + (size_t)br1 * K + sx * 8;

#define STAGE(tile_) do { if ((tile_) < nkt) { int par_ = (tile_) & 1; \
    gload_lds16(pA,  &Abuf[par_][ldsoff]); \
    gload_lds16(pB0, &Bbuf[par_][0][ldsoff]); \
    gload_lds16(pB1, &Bbuf[par_][1][ldsoff]); \
    pA += 32; pB0 += 32; pB1 += 32; } } while (0)

  const int aro = (wm * 64 + lr) * 32;
  const int bro = (wn * 32 + lr) * 32;
  const int so = (kg ^ ((lr >> 1) & 3)) * 8;

  s16x8 a[4], b0[2], b1[2];
#define LDFRAGS(par_) do { \
    _Pragma("unroll") \
    for (int m_ = 0; m_ < 4; ++m_) a[m_] = *(const s16x8*)&Abuf[par_][aro + m_ * 512 + so]; \
    _Pragma("unroll") \
    for (int n_ = 0; n_ < 2; ++n_) { \
      b0[n_] = *(const s16x8*)&Bbuf[par_][0][bro + n_ * 512 + so]; \
      b1[n_] = *(const s16x8*)&Bbuf[par_][1][bro + n_ * 512 + so]; \
    } } while (0)

  f32x4 acc[2][4][2];
  #pragma unroll
  for (int h_ = 0; h_ < 2; ++h_)
    #pragma unroll
    for (int m_ = 0; m_ < 4; ++m_)
      #pragma unroll
      for (int n_ = 0; n_ < 2; ++n_) acc[h_][m_][n_] = (f32x4){0.f, 0.f, 0.f, 0.f};

  STAGE(0);
  VMW0();
  BARR();

  for (int g = 0; g < nkt; ++g) {
    const int par = g & 1;
    LDFRAGS(par);
    STAGE(g + 1);
    __builtin_amdgcn_s_setprio(1);
    #pragma unroll
    for (int m_ = 0; m_ < 4; ++m_)
      #pragma unroll
      for (int n_ = 0; n_ < 2; ++n_) {
        acc[0][m_][n_] = __builtin_amdgcn_mfma_f32_16x16x32_bf16(a[m_], b0[n_], acc[0][m_][n_], 0, 0, 0);
        acc[1][m_][n_] = __builtin_amdgcn_mfma_f32_16x16x32_bf16(a[m_], b1[n_], acc[1][m_][n_], 0, 0, 0);
      }
    __builtin_amdgcn_s_setprio(0);
    VMW0();
    BARR();
  }

  #pragma unroll
  for (int nh = 0; nh < 2; ++nh)
    #pragma unroll
    for (int n_ = 0; n_ < 2; ++n_) {
      int col = bN + nh * 128 + wn * 32 + n_ * 16 + lr;
      if (NTAIL && col >= N) continue;
      float bv = bias[col];
      #pragma unroll
      for (int m_ = 0; m_ < 4; ++m_) {
        int row0 = bM + wm * 64 + m_ * 16 + kg * 4;
        #pragma unroll
        for (int r_ = 0; r_ < 4; ++r_) {
          float v = acc[nh][m_][n_][r_] + bv;
          if (RELU) v = fmaxf(v, 0.f);
          size_t off = (size_t)(row0 + r_) * ldc + col;
          if (F32OUT) ((float*)Cout + (size_t)z * cZ)[off] = v;
          else        ((short*)Cout + (size_t)z * cZ)[off] = f2b(v);
        }
      }
    }
#undef STAGE
#undef LDFRAGS
}

// ---------------- mean over 9 patch rows (vectorized s16x8) ----------------
__global__ void mean9_kernel(const short* __restrict__ h, short* __restrict__ hm) {
  size_t i = (size_t)blockIdx.x * blockDim.x + threadIdx.x;
  if (i >= (size_t)kB * kENCH / 8) return;
  size_t b = i >> 6; int d8 = (int)(i & 63);
  const short* base = h + b * kP * kENCH + d8 * 8;
  float s[8] = {0, 0, 0, 0, 0, 0, 0, 0};
  #pragma unroll
  for (int p = 0; p < kP; ++p) {
    s16x8 v = *(const s16x8*)(base + p * kENCH);
    #pragma unroll
    for (int j = 0; j < 8; ++j) s[j] += b2f(v[j]);
  }
  s16x8 o;
  #pragma unroll
  for (int j = 0; j < 8; ++j) o[j] = f2b(s[j] * (1.f / 9.f));
  *(s16x8*)(hm + i * 8) = o;
}

// ---------------- fused gating: neural L2 + symbolic MLP + softmax --------
__global__ __launch_bounds__(256)
void gating_fused_kernel(const short* __restrict__ gh,
                         const float* __restrict__ gn_w2, const float* __restrict__ gn_b2,
                         const float* __restrict__ sym,
                         const float* __restrict__ gs_w1, const float* __restrict__ gs_b1,
                         const float* __restrict__ gs_w2, const float* __restrict__ gs_b2,
                         float* __restrict__ gate_out) {
  int wid = threadIdx.x >> 6, lane = threadIdx.x & 63;
  int row = blockIdx.x * 4 + wid;
  float acc[8] = {0,0,0,0,0,0,0,0};
  const short* grow = gh + (size_t)row * kD;
  for (int k = lane; k < kD; k += 64) {
    float x = b2f(grow[k]);
    const float* w = gn_w2 + (size_t)k * 8;
    #pragma unroll
    for (int c = 0; c < 8; ++c) acc[c] += x * w[c];
  }
  float s0 = sym[(size_t)row * 6 + 0], s1 = sym[(size_t)row * 6 + 1], s2 = sym[(size_t)row * 6 + 2];
  float s3 = sym[(size_t)row * 6 + 3], s4 = sym[(size_t)row * 6 + 4], s5 = sym[(size_t)row * 6 + 5];
  float hh = gs_b1[lane];
  hh += s0 * gs_w1[0 * 64 + lane] + s1 * gs_w1[1 * 64 + lane] + s2 * gs_w1[2 * 64 + lane];
  hh += s3 * gs_w1[3 * 64 + lane] + s4 * gs_w1[4 * 64 + lane] + s5 * gs_w1[5 * 64 + lane];
  hh = fmaxf(hh, 0.f);
  float acc2[8];
  #pragma unroll
  for (int c = 0; c < 8; ++c) acc2[c] = hh * gs_w2[lane * 8 + c];
  #pragma unroll
  for (int c = 0; c < 8; ++c)
    #pragma unroll
    for (int off = 32; off >= 1; off >>= 1) {
      acc[c]  += __shfl_xor(acc[c], off);
      acc2[c] += __shfl_xor(acc2[c], off);
    }
  if (lane == 0) {
    float g[8], m = -1e30f;
    #pragma unroll
    for (int c = 0; c < 8; ++c) {
      g[c] = 0.5f * ((acc[c] + gn_b2[c]) + (acc2[c] + gs_b2[c]));
      m = fmaxf(m, g[c]);
    }
    float sum = 0.f;
    #pragma unroll
    for (int c = 0; c < 8; ++c) { g[c] = expf(g[c] - m); sum += g[c]; }
    float inv = 1.f / sum;
    #pragma unroll
    for (int c = 0; c < 8; ++c) gate_out[(size_t)row * 8 + c] = g[c] * inv;
  }
}

// ---------------- logits[b,c] = sum_e gate[b,e] * EL[b,e,c] ----------------
__global__ __launch_bounds__(256)
void combine_kernel(float* __restrict__ out) {
  int b = blockIdx.y;
  int c = blockIdx.x * 256 + threadIdx.x;
  __shared__ float g[8];
  if (threadIdx.x < 8) g[threadIdx.x] = out[OUT_GATE + (size_t)b * 8 + threadIdx.x];
  __syncthreads();
  if (c < kC) {
    const float* el = out + OUT_EL + (size_t)b * (kE * kC) + c;
    float a = 0.f;
    #pragma unroll
    for (int e = 0; e < 8; ++e) a += g[e] * el[e * kC];
    out[(size_t)b * kC + c] = a;
  }
}

extern "C" void kernel_launch(void* const* d_in, const int* in_sizes, int n_in,
                              void* d_out, int out_size, void* d_ws, size_t ws_size,
                              hipStream_t stream) {
  const float* patches = (const float*)d_in[0];
  const float* symf    = (const float*)d_in[1];
  const float* enc_w1  = (const float*)d_in[2];
  const float* enc_b1  = (const float*)d_in[3];
  const float* enc_w2  = (const float*)d_in[4];
  const float* enc_b2  = (const float*)d_in[5];
  const float* gn_w1   = (const float*)d_in[6];
  const float* gn_b1   = (const float*)d_in[7];
  const float* gn_w2   = (const float*)d_in[8];
  const float* gn_b2   = (const float*)d_in[9];
  const float* gs_w1   = (const float*)d_in[10];
  const float* gs_b1   = (const float*)d_in[11];
  const float* gs_w2   = (const float*)d_in[12];
  const float* gs_b2   = (const float*)d_in[13];
  const float* ew1     = (const float*)d_in[14];
  const float* eb1     = (const float*)d_in[15];
  const float* ew2     = (const float*)d_in[16];
  const float* eb2     = (const float*)d_in[17];
  char* ws = (char*)d_ws;
  float* out = (float*)d_out;
  dim3 tb(32, 8);

  // 1. cast patches to bf16 (viewed as 73728 x 768)
  {
    size_t n8 = (size_t)kB * kP * kDIN / 8;
    cast_bf16_kernel<<<(unsigned)((n8 + 255) / 256), 256, 0, stream>>>(patches, (short*)(ws + PBF), n8);
  }
  // 2. transpose-cast weights to (N x K) bf16
  transpose_cast_kernel<<<dim3(16, 24, 1), tb, 0, stream>>>(enc_w1, (short*)(ws + W1T),  kDIN,  kENCH, 0, 0);
  transpose_cast_kernel<<<dim3(32, 16, 1), tb, 0, stream>>>(enc_w2, (short*)(ws + W2T),  kENCH, kD,    0, 0);
  transpose_cast_kernel<<<dim3(32, 32, 1), tb, 0, stream>>>(gn_w1,  (short*)(ws + GW1T), kD,    kD,    0, 0);
  transpose_cast_kernel<<<dim3(64, 32, 8), tb, 0, stream>>>(ew1,    (short*)(ws + EW1T), kD,    kH,
                                                            (size_t)kD * kH, (size_t)kD * kH);
  transpose_cast_kernel<<<dim3(32, 64, 8), tb, 0, stream>>>(ew2,    (short*)(ws + EW2T), kH,    kC,
                                                            (size_t)kH * kC, (size_t)kH * kC);
  // 3. encoder L1 (256^2): (73728x768) @ (768x512)^T + b, ReLU -> HBUF
  gemm256_kernel<true, false, false><<<dim3(2, 288, 1), 512, 0, stream>>>(
      (short*)(ws + PBF), (short*)(ws + W1T), enc_b1, ws + HBUF,
      kB * kP, kENCH, kDIN, kENCH, 0, 0, 0, 0);
  // 4. mean over 9 patches -> hmean
  mean9_kernel<<<(kB * kENCH / 8) / 256, 256, 0, stream>>>((short*)(ws + HBUF), (short*)(ws + HMEAN));
  // 5. encoder L2 (128-tile, full-machine grid): (8192x512)@(512x1024)^T -> agg
  gemm128_kernel<false, false, false><<<dim3(4, 64, 1), 512, 0, stream>>>(
      (short*)(ws + HMEAN), (short*)(ws + W2T), enc_b2, ws + AGG,
      kB, kD, kENCH, kD, 0, 0, 0, 0);
  // 6. neural gating L1 (128-tile): (8192x1024)@(1024x1024)^T, ReLU -> gh
  gemm128_kernel<true, false, false><<<dim3(4, 64, 1), 512, 0, stream>>>(
      (short*)(ws + AGG), (short*)(ws + GW1T), gn_b1, ws + GH,
      kB, kD, kD, kD, 0, 0, 0, 0);
  // 7. fused gating (neural L2 + symbolic + softmax) -> d_out gate
  gating_fused_kernel<<<kB / 4, 256, 0, stream>>>(
      (short*)(ws + GH), gn_w2, gn_b2, symf, gs_w1, gs_b1, gs_w2, gs_b2, out + OUT_GATE);
  // 8-9. experts: z=8 single dispatch per layer if ws allows, else 2x z=4
  if (ws_size >= WS_Z8) {
    gemm256_kernel<true, false, false><<<dim3(8, 32, 8), 512, 0, stream>>>(
        (short*)(ws + AGG), (short*)(ws + EW1T), eb1,
        ws + EH4, kB, kH, kD, kH,
        0, (long)kH * kD, kH, (long)kB * kH);
    gemm256_kernel<false, true, true><<<dim3(4, 32, 8), 512, 0, stream>>>(
        (short*)(ws + EH4), (short*)(ws + EW2T), eb2,
        out + OUT_EL, kB, kC, kH, kE * kC,
        (long)kB * kH, (long)kC * kH, kC, kC);
  } else {
    for (int h = 0; h < 2; ++h) {
      int e0 = h * 4;
      gemm256_kernel<true, false, false><<<dim3(8, 32, 4), 512, 0, stream>>>(
          (short*)(ws + AGG), (short*)(ws + EW1T) + (size_t)e0 * kH * kD, eb1 + (size_t)e0 * kH,
          ws + EH4, kB, kH, kD, kH,
          0, (long)kH * kD, kH, (long)kB * kH);
      gemm256_kernel<false, true, true><<<dim3(4, 32, 4), 512, 0, stream>>>(
          (short*)(ws + EH4), (short*)(ws + EW2T) + (size_t)e0 * kC * kH, eb2 + (size_t)e0 * kC,
          out + OUT_EL + (size_t)e0 * kC, kB, kC, kH, kE * kC,
          (long)kB * kH, (long)kC * kH, kC, kC);
    }
  }
  // 10. combine
  combine_kernel<<<dim3(4, kB), 256, 0, stream>>>(out);
}